// Round 6
// baseline (101.963 us; speedup 1.0000x reference)
//
#include <hip/hip_runtime.h>
#include <stdint.h>

// ============================================================================
// MoE collapses exactly to: out = relu(x @ w1) @ w2   (round-0 analysis)
//   - shared expert weights => both top-2 slots compute identical f(x[s])
//   - g1+g2 normalized to 1 => combine gather returns f(x[s])
//   - capacity = S and count1+count2 <= S => no token dropped
// Wg is unused.
//
// Round-5 -> 6: GEMMs are staging-BW-bound (201 MB staged per GEMM at
// 128x256 tiles; MFMA/LDS cycle budgets far below staging time). Move to
// 256x256 tiles: FLOP/staged-byte 85 -> 171, staged 201 -> 134 MB/GEMM.
// Grid drops to 128 blocks (BW is chip-level, so fewer fatter blocks win
// if the BW theory is right). BK=64, LDS double-buffer 128 KB, 8 waves
// (2x4) x per-wave 128x64, depth-2 counted vmcnt(8); second barrier after
// lgkmcnt(0) lets stage(t+2) overwrite the just-read buffer safely.
// T2 swizzle / T5 setprio / XCD 4x4 chunking carried over.
// ============================================================================

typedef __attribute__((ext_vector_type(4))) float f32x4;
typedef __attribute__((ext_vector_type(16))) float f32x16;
typedef __attribute__((ext_vector_type(8))) short bf16x8;

#define GPTR(p) (const __attribute__((address_space(1))) void*)(p)
#define LPTR(p) (__attribute__((address_space(3))) void*)(p)

__device__ __forceinline__ ushort f2bf(float f) {
  uint32_t u = __float_as_uint(f);
  uint32_t r = (u + 0x7FFFu + ((u >> 16) & 1u)) >> 16;  // RNE
  return (ushort)r;
}
__device__ __forceinline__ float bf2f(ushort u) {
  return __uint_as_float((uint32_t)u << 16);
}

// ---- fused prep: x->bf16, w1->w1t (bf16, transposed), w2->w2t ---------------
__device__ __forceinline__ void tile_transpose(const float* __restrict__ in,
                                               ushort* __restrict__ out,
                                               int R, int C, int bx, int by,
                                               int tx, int ty) {
  __shared__ float tile[32][33];
  const int c0 = bx * 32, r0 = by * 32;
#pragma unroll
  for (int i = 0; i < 32; i += 8)
    tile[ty + i][tx] = in[(size_t)(r0 + ty + i) * C + (c0 + tx)];
  __syncthreads();
#pragma unroll
  for (int i = 0; i < 32; i += 8)
    out[(size_t)(c0 + ty + i) * R + (r0 + tx)] = f2bf(tile[tx][ty + i]);
}

__global__ void prep(const float* __restrict__ x, const float* __restrict__ w1,
                     const float* __restrict__ w2, ushort* __restrict__ xb,
                     ushort* __restrict__ w1t, ushort* __restrict__ w2t) {
  const int b = blockIdx.x;
  const int tx = threadIdx.x, ty = threadIdx.y;  // (32,8)
  if (b < 2048) {  // cvt: x -> xb
    int i = b * 256 + ty * 32 + tx;
    float4 v = ((const float4*)x)[i];
    ushort4 o;
    o.x = f2bf(v.x); o.y = f2bf(v.y); o.z = f2bf(v.z); o.w = f2bf(v.w);
    ((ushort4*)xb)[i] = o;
  } else if (b < 6144) {  // w1 [1024][4096] -> w1t [4096][1024]
    int b2 = b - 2048;
    tile_transpose(w1, w1t, 1024, 4096, b2 & 127, b2 >> 7, tx, ty);
  } else {  // w2 [4096][1024] -> w2t [1024][4096]
    int b3 = b - 6144;
    tile_transpose(w2, w2t, 4096, 1024, b3 & 31, b3 >> 5, tx, ty);
  }
}

// ---- out += sum of 3 bf16 partials -----------------------------------------
__global__ void reduce_out(float* __restrict__ out, const ushort* __restrict__ pb,
                           int SD) {
  int i = blockIdx.x * blockDim.x + threadIdx.x;  // 4 floats / thread
  if (i >= SD / 4) return;
  f32x4 a = ((const f32x4*)out)[i];
#pragma unroll
  for (int j = 0; j < 3; ++j) {
    ushort4 u = ((const ushort4*)(pb + (size_t)j * SD))[i];
    a[0] += bf2f(u.x); a[1] += bf2f(u.y); a[2] += bf2f(u.z); a[3] += bf2f(u.w);
  }
  ((f32x4*)out)[i] = a;
}

// ---- bf16 GEMM, B transposed ([N][K]); 256^2 tile, counted-vmcnt pipeline ---
// MODE 1: C0 = relu(A@Bt^T) as bf16.  MODE 2: split-K; bz==0 -> fp32 C0,
// bz>0 -> bf16 partial C1 + (bz-1)*M*N.
// 8 waves 2x4, per-wave 128x64 (4x2 32x32 frags). LDS 2 x (32+32) KB.
// Chunking: each XCD (blockIdx.x & 7) owns a 4bx x 4by sub-grid.
template <int MODE>
__global__ __launch_bounds__(512) void gemm_pipe(const ushort* __restrict__ A,
                                                 const ushort* __restrict__ Bt,
                                                 void* __restrict__ C0,
                                                 void* __restrict__ C1,
                                                 int M, int N, int Ks, int Ktot,
                                                 int ncx, int cpz) {
  constexpr int BM = 256, BN = 256, BK = 64;
  __shared__ ushort As[2][BM * BK];  // 2 x 32 KB
  __shared__ ushort Bs[2][BN * BK];  // 2 x 32 KB   (total 128 KB)

  const int tid = threadIdx.x;
  const int lane = tid & 63, wid = tid >> 6;  // 8 waves
  const int wr = wid >> 2, wc = wid & 3;      // 2 x 4 wave grid, 128x64 each

  // XCD chunking: chunk = blockIdx.x & 7 (round-robin XCD), 16 blocks/chunk
  // arranged 4(bx) x 4(by).
  const int ck = blockIdx.x & 7;
  const int w = blockIdx.x >> 3;  // 0..15
  const int bz = ck / cpz;
  const int rem = ck % cpz;
  const int bx = (rem % ncx) * 4 + (w & 3);
  const int by = (rem / ncx) * 4 + (w >> 2);
  const int row0 = by * BM, col0 = bx * BN;
  const int kbase = bz * Ks;

  f32x16 acc[4][2];
#pragma unroll
  for (int m = 0; m < 4; ++m)
#pragma unroll
    for (int n = 0; n < 2; ++n) acc[m][n] = (f32x16)(0.f);

  // stage: 8 global_load_lds x 16B per thread (A 4 issues + B 4 issues).
  // LDS dest LINEAR; source col XOR-swizzled (rule #21, verified r4/r5).
  const int rA = tid >> 3;        // 0..63 row within an 8KB issue
  const int cb = (tid & 7) * 16;  // byte col within 128B row
  auto stage = [&](int buf, int k0) {
#pragma unroll
    for (int i = 0; i < 4; ++i) {  // A: 256 rows
      int r = i * 64 + rA;
      int csw = cb ^ ((r & 7) << 4);
      __builtin_amdgcn_global_load_lds(
          GPTR((const char*)(A + (size_t)(row0 + r) * Ktot + k0) + csw),
          LPTR((char*)&As[buf][0] + i * 8192 + wid * 1024), 16, 0, 0);
    }
#pragma unroll
    for (int j = 0; j < 4; ++j) {  // B: 256 rows
      int r = j * 64 + rA;
      int csw = cb ^ ((r & 7) << 4);
      __builtin_amdgcn_global_load_lds(
          GPTR((const char*)(Bt + (size_t)(col0 + r) * Ktot + k0) + csw),
          LPTR((char*)&Bs[buf][0] + j * 8192 + wid * 1024), 16, 0, 0);
    }
  };

  const int nt = Ks / BK;  // 16 for both GEMMs
  stage(0, kbase);
  stage(1, kbase + BK);

  for (int t = 0; t < nt; ++t) {
    // own tile-t loads landed (8 of t+1's still in flight) ...
    if (t < nt - 1) asm volatile("s_waitcnt vmcnt(8)" ::: "memory");
    else            asm volatile("s_waitcnt vmcnt(0)" ::: "memory");
    __builtin_amdgcn_sched_barrier(0);
    __builtin_amdgcn_s_barrier();  // ... and now ALL waves' tile-t loads landed
    __builtin_amdgcn_sched_barrier(0);

    const ushort* Ab = As[t & 1];
    const ushort* Bb = Bs[t & 1];
    bf16x8 a[4][4], b[4][2];  // [k-slice][frag]
#pragma unroll
    for (int s = 0; s < 4; ++s) {
      const int kb2 = s * 32 + (lane >> 5) * 16;
#pragma unroll
      for (int m = 0; m < 4; ++m) {
        int R = wr * 128 + m * 32 + (lane & 31);
        a[s][m] = *(const bf16x8*)((const char*)Ab + R * 128 + (kb2 ^ ((R & 7) << 4)));
      }
#pragma unroll
      for (int n = 0; n < 2; ++n) {
        int R = wc * 64 + n * 32 + (lane & 31);
        b[s][n] = *(const bf16x8*)((const char*)Bb + R * 128 + (kb2 ^ ((R & 7) << 4)));
      }
    }
    asm volatile("s_waitcnt lgkmcnt(0)" ::: "memory");
    __builtin_amdgcn_sched_barrier(0);
    __builtin_amdgcn_s_barrier();  // all waves done READING buf[t&1]
    __builtin_amdgcn_sched_barrier(0);
    // safe to overwrite the just-read buffer; loads overlap the MFMAs below
    if (t + 2 < nt) stage(t & 1, kbase + (size_t)(t + 2) * BK);

    __builtin_amdgcn_s_setprio(1);
#pragma unroll
    for (int s = 0; s < 4; ++s)
#pragma unroll
      for (int m = 0; m < 4; ++m)
#pragma unroll
        for (int n = 0; n < 2; ++n)
          acc[m][n] = __builtin_amdgcn_mfma_f32_32x32x16_bf16(a[s][m], b[s][n], acc[m][n], 0, 0, 0);
    __builtin_amdgcn_s_setprio(0);
  }

  // epilogue; 32x32 C/D layout (m74/m101-verified):
  //   col = lane&31, row = (r&3) + 8*(r>>2) + 4*(lane>>5)
  const int rbase = row0 + wr * 128, cbase = col0 + wc * 64;
#pragma unroll
  for (int m = 0; m < 4; ++m) {
#pragma unroll
    for (int n = 0; n < 2; ++n) {
      const int col = cbase + n * 32 + (lane & 31);
#pragma unroll
      for (int r = 0; r < 16; ++r) {
        const int row = rbase + m * 32 + (r & 3) + 8 * (r >> 2) + 4 * (lane >> 5);
        float v = acc[m][n][r];
        size_t idx = (size_t)row * N + col;
        if (MODE == 1) {
          v = v > 0.f ? v : 0.f;
          ((ushort*)C0)[idx] = f2bf(v);
        } else {
          if (bz == 0)
            ((float*)C0)[idx] = v;
          else
            ((ushort*)C1)[(size_t)(bz - 1) * M * N + idx] = f2bf(v);
        }
      }
    }
  }
}

extern "C" void kernel_launch(void* const* d_in, const int* in_sizes, int n_in,
                              void* d_out, int out_size, void* d_ws, size_t ws_size,
                              hipStream_t stream) {
  const float* x  = (const float*)d_in[0];
  // d_in[1] (Wg) is provably unused: gating collapses to identity (see header)
  const float* w1 = (const float*)d_in[2];
  const float* w2 = (const float*)d_in[3];
  float* out = (float*)d_out;

  constexpr int S = 2048, D = 1024, F = 4096;
  char* ws = (char*)d_ws;
  ushort* xb  = (ushort*)(ws);                                    // [S][D]  4 MB
  ushort* w1t = (ushort*)(ws + (size_t)S * D * 2);                // [F][D]  8 MB
  ushort* w2t = (ushort*)(ws + (size_t)(S * D + F * D) * 2);      // [D][F]  8 MB
  ushort* H   = (ushort*)(ws + (size_t)(S * D + 2 * F * D) * 2);  // [S][F] 16 MB
  // 3 bf16 split-K partials (12 MB) overlay xb+w1t (dead after GEMM1).
  ushort* pb = (ushort*)(ws);

  // fused prep: 2048 cvt blocks + 4096 w1-transpose + 4096 w2-transpose
  hipLaunchKernelGGL(prep, dim3(10240), dim3(32, 8), 0, stream,
                     x, w1, w2, xb, w1t, w2t);
  // GEMM1: H = relu(xb @ w1t^T)  [2048 x 4096], K=1024
  //   tiles 16(bx) x 8(by) = 128 blocks; chunks: ncx=4, cpz=8 (nz=1)
  hipLaunchKernelGGL((gemm_pipe<1>), dim3(128), dim3(512), 0, stream,
                     xb, w1t, (void*)H, nullptr, S, F, D, D, 4, 8);
  // GEMM2: out = H @ w2t^T  [2048 x 1024], K=4096 split 4x1024
  //   tiles 4 x 8 x z4 = 128 blocks; chunks: ncx=1, cpz=2 (nz=4)
  hipLaunchKernelGGL((gemm_pipe<2>), dim3(128), dim3(512), 0, stream,
                     H, w2t, (void*)out, (void*)pb, S, D, F / 4, F, 1, 2);
  // out += p1 + p2 + p3
  hipLaunchKernelGGL(reduce_out, dim3((S * D / 4 + 255) / 256), dim3(256), 0, stream,
                     out, pb, S * D);
}

// Round 7
// 69.836 us; speedup vs baseline: 1.4600x; 1.4600x over previous
//
#include <hip/hip_runtime.h>
#include <stdint.h>

// ============================================================================
// MoE collapses exactly to: out = relu(x @ w1) @ w2   (round-0 analysis)
//   - shared expert weights => both top-2 slots compute identical f(x[s])
//   - g1+g2 normalized to 1 => combine gather returns f(x[s])
//   - capacity = S and count1+count2 <= S => no token dropped
// Wg is unused.
//
// Round-6 -> 7: r6 (256^2 tiles) FALSIFIED the staging-BW theory: FETCH
// dropped to 16.5 MB but time doubled (half-chip grid + coarse read/MFMA
// phases = stall-bound, m196's regression). Revert to r5 geometry
// (128x256, 256 blocks, 3-buffer counted vmcnt(6)) and add the m196 fine
// interleave INSIDE each K-step:
//   - software-pipeline k-slices: read slice s+1 frags before MFMA slice s
//     (compiler emits counted lgkmcnt -> reads overlap MFMAs)
//   - spread the 6 stage(t+2) global_load_lds across slices (2 per slice)
// Sync structure identical to r5 (verified). T1/T2/T5 carried over.
// ============================================================================

typedef __attribute__((ext_vector_type(4))) float f32x4;
typedef __attribute__((ext_vector_type(16))) float f32x16;
typedef __attribute__((ext_vector_type(8))) short bf16x8;

#define GPTR(p) (const __attribute__((address_space(1))) void*)(p)
#define LPTR(p) (__attribute__((address_space(3))) void*)(p)

__device__ __forceinline__ ushort f2bf(float f) {
  uint32_t u = __float_as_uint(f);
  uint32_t r = (u + 0x7FFFu + ((u >> 16) & 1u)) >> 16;  // RNE
  return (ushort)r;
}
__device__ __forceinline__ float bf2f(ushort u) {
  return __uint_as_float((uint32_t)u << 16);
}

// ---- fused prep: x->bf16, w1->w1t (bf16, transposed), w2->w2t ---------------
__device__ __forceinline__ void tile_transpose(const float* __restrict__ in,
                                               ushort* __restrict__ out,
                                               int R, int C, int bx, int by,
                                               int tx, int ty) {
  __shared__ float tile[32][33];
  const int c0 = bx * 32, r0 = by * 32;
#pragma unroll
  for (int i = 0; i < 32; i += 8)
    tile[ty + i][tx] = in[(size_t)(r0 + ty + i) * C + (c0 + tx)];
  __syncthreads();
#pragma unroll
  for (int i = 0; i < 32; i += 8)
    out[(size_t)(c0 + ty + i) * R + (r0 + tx)] = f2bf(tile[tx][ty + i]);
}

__global__ void prep(const float* __restrict__ x, const float* __restrict__ w1,
                     const float* __restrict__ w2, ushort* __restrict__ xb,
                     ushort* __restrict__ w1t, ushort* __restrict__ w2t) {
  const int b = blockIdx.x;
  const int tx = threadIdx.x, ty = threadIdx.y;  // (32,8)
  if (b < 2048) {  // cvt: x -> xb
    int i = b * 256 + ty * 32 + tx;
    float4 v = ((const float4*)x)[i];
    ushort4 o;
    o.x = f2bf(v.x); o.y = f2bf(v.y); o.z = f2bf(v.z); o.w = f2bf(v.w);
    ((ushort4*)xb)[i] = o;
  } else if (b < 6144) {  // w1 [1024][4096] -> w1t [4096][1024]
    int b2 = b - 2048;
    tile_transpose(w1, w1t, 1024, 4096, b2 & 127, b2 >> 7, tx, ty);
  } else {  // w2 [4096][1024] -> w2t [1024][4096]
    int b3 = b - 6144;
    tile_transpose(w2, w2t, 4096, 1024, b3 & 31, b3 >> 5, tx, ty);
  }
}

// ---- out += sum of 3 bf16 partials -----------------------------------------
__global__ void reduce_out(float* __restrict__ out, const ushort* __restrict__ pb,
                           int SD) {
  int i = blockIdx.x * blockDim.x + threadIdx.x;  // 4 floats / thread
  if (i >= SD / 4) return;
  f32x4 a = ((const f32x4*)out)[i];
#pragma unroll
  for (int j = 0; j < 3; ++j) {
    ushort4 u = ((const ushort4*)(pb + (size_t)j * SD))[i];
    a[0] += bf2f(u.x); a[1] += bf2f(u.y); a[2] += bf2f(u.z); a[3] += bf2f(u.w);
  }
  ((f32x4*)out)[i] = a;
}

// ---- bf16 GEMM, B transposed ([N][K]); counted-vmcnt + fine interleave ------
// MODE 1: C0 = relu(A@Bt^T) as bf16.  MODE 2: split-K; bz==0 -> fp32 C0,
// bz>0 -> bf16 partial C1 + (bz-1)*M*N.
// BM=128 x BN=256 x BK=64, 8 waves (2x4), per-wave 64x64 (2x2 32x32 frags).
// 3-buffer LDS (144 KB), depth-2 prefetch, steady-state s_waitcnt vmcnt(6),
// ONE barrier per K-step. K-step = 4 k-slices, software-pipelined:
// read slice s+1 (4 ds_read_b128) + 2 stage loads, then 4 MFMAs of slice s.
template <int MODE>
__global__ __launch_bounds__(512) void gemm_pipe(const ushort* __restrict__ A,
                                                 const ushort* __restrict__ Bt,
                                                 void* __restrict__ C0,
                                                 void* __restrict__ C1,
                                                 int M, int N, int Ks, int Ktot,
                                                 int ncx, int cpz) {
  constexpr int BM = 128, BN = 256, BK = 64;
  __shared__ ushort As[3][BM * BK];  // 3 x 16 KB
  __shared__ ushort Bs[3][BN * BK];  // 3 x 32 KB   (total 144 KB)

  const int tid = threadIdx.x;
  const int lane = tid & 63, wid = tid >> 6;  // 8 waves
  const int wr = wid >> 2, wc = wid & 3;      // 2 x 4 wave grid

  // T1 (2D-chunked): chunk (=XCD) = blockIdx.x & 7, 32 blocks/chunk -> 4x8.
  const int ck = blockIdx.x & 7;
  const int w = blockIdx.x >> 3;
  const int bz = ck / cpz;
  const int rem = ck % cpz;
  const int bx = (rem % ncx) * 4 + (w & 3);
  const int by = (rem / ncx) * 8 + (w >> 2);
  const int row0 = by * BM, col0 = bx * BN;
  const int kbase = bz * Ks;

  f32x16 acc[2][2];
#pragma unroll
  for (int m = 0; m < 2; ++m)
#pragma unroll
    for (int n = 0; n < 2; ++n) acc[m][n] = (f32x16)(0.f);

  // staging: 6 global_load_lds x 16B per thread (A 2 issues + B 4 issues).
  // LDS dest LINEAR; source col XOR-swizzled (rule #21, verified r4/r5).
  const int rA = tid >> 3;        // 0..63 row within an 8KB issue
  const int cb = (tid & 7) * 16;  // byte col within 128B row
  // part p in {0,1,2}: p==0 -> A issues 0,1; p==1 -> B issues 0,1; p==2 -> B 2,3
  auto stage_part = [&](int buf, int k0, int p) {
    if (p == 0) {
#pragma unroll
      for (int i = 0; i < 2; ++i) {
        int r = i * 64 + rA;
        int csw = cb ^ ((r & 7) << 4);
        __builtin_amdgcn_global_load_lds(
            GPTR((const char*)(A + (size_t)(row0 + r) * Ktot + k0) + csw),
            LPTR((char*)&As[buf][0] + i * 8192 + wid * 1024), 16, 0, 0);
      }
    } else {
#pragma unroll
      for (int j2 = 0; j2 < 2; ++j2) {
        int j = (p - 1) * 2 + j2;
        int r = j * 64 + rA;
        int csw = cb ^ ((r & 7) << 4);
        __builtin_amdgcn_global_load_lds(
            GPTR((const char*)(Bt + (size_t)(col0 + r) * Ktot + k0) + csw),
            LPTR((char*)&Bs[buf][0] + j * 8192 + wid * 1024), 16, 0, 0);
      }
    }
  };
  auto stage = [&](int buf, int k0) {
    stage_part(buf, k0, 0); stage_part(buf, k0, 1); stage_part(buf, k0, 2);
  };

  const int nt = Ks / BK;  // 16 for both GEMMs
  stage(0, kbase);
  stage(1, kbase + BK);

  for (int t = 0; t < nt; ++t) {
    // own tile-t loads landed; tile t+1's 6 stay in flight across the barrier
    if (t < nt - 1) asm volatile("s_waitcnt vmcnt(6)" ::: "memory");
    else            asm volatile("s_waitcnt vmcnt(0)" ::: "memory");
    __builtin_amdgcn_sched_barrier(0);
    __builtin_amdgcn_s_barrier();   // all waves: tile-t resident, buf[(t+2)%3]
                                    // free (its readers finished at step t-1)
    __builtin_amdgcn_sched_barrier(0);

    const ushort* Ab = As[t % 3];
    const ushort* Bb = Bs[t % 3];
    const bool pf = (t + 2 < nt);
    const int knext = kbase + (t + 2) * BK;
    const int pbuf = (t + 2) % 3;

    // 2-slice register pipeline: read s+1 while MFMA s (static idx, rule #20)
    bf16x8 a[2][2], b[2][2];
    auto read_slice = [&](int s, int sb) {
      const int kb2 = s * 32 + (lane >> 5) * 16;
#pragma unroll
      for (int m = 0; m < 2; ++m) {
        int R = wr * 64 + m * 32 + (lane & 31);
        a[sb][m] = *(const bf16x8*)((const char*)Ab + R * 128 + (kb2 ^ ((R & 7) << 4)));
      }
#pragma unroll
      for (int n = 0; n < 2; ++n) {
        int R = wc * 64 + n * 32 + (lane & 31);
        b[sb][n] = *(const bf16x8*)((const char*)Bb + R * 128 + (kb2 ^ ((R & 7) << 4)));
      }
    };

    read_slice(0, 0);
#pragma unroll
    for (int s = 0; s < 4; ++s) {
      if (s < 3) read_slice(s + 1, (s + 1) & 1);   // reads fly over MFMAs below
      if (s < 3 && pf) stage_part(pbuf, knext, s); // spread VMEM issue (m196)
      __builtin_amdgcn_s_setprio(1);
#pragma unroll
      for (int m = 0; m < 2; ++m)
#pragma unroll
        for (int n = 0; n < 2; ++n)
          acc[m][n] = __builtin_amdgcn_mfma_f32_32x32x16_bf16(a[s & 1][m], b[s & 1][n],
                                                              acc[m][n], 0, 0, 0);
      __builtin_amdgcn_s_setprio(0);
    }
  }

  // epilogue; 32x32 C/D layout (m74/m101-verified):
  //   col = lane&31, row = (r&3) + 8*(r>>2) + 4*(lane>>5)
  const int rbase = row0 + wr * 64, cbase = col0 + wc * 64;
#pragma unroll
  for (int m = 0; m < 2; ++m) {
#pragma unroll
    for (int n = 0; n < 2; ++n) {
      const int col = cbase + n * 32 + (lane & 31);
#pragma unroll
      for (int r = 0; r < 16; ++r) {
        const int row = rbase + m * 32 + (r & 3) + 8 * (r >> 2) + 4 * (lane >> 5);
        float v = acc[m][n][r];
        size_t idx = (size_t)row * N + col;
        if (MODE == 1) {
          v = v > 0.f ? v : 0.f;
          ((ushort*)C0)[idx] = f2bf(v);
        } else {
          if (bz == 0)
            ((float*)C0)[idx] = v;
          else
            ((ushort*)C1)[(size_t)(bz - 1) * M * N + idx] = f2bf(v);
        }
      }
    }
  }
}

extern "C" void kernel_launch(void* const* d_in, const int* in_sizes, int n_in,
                              void* d_out, int out_size, void* d_ws, size_t ws_size,
                              hipStream_t stream) {
  const float* x  = (const float*)d_in[0];
  // d_in[1] (Wg) is provably unused: gating collapses to identity (see header)
  const float* w1 = (const float*)d_in[2];
  const float* w2 = (const float*)d_in[3];
  float* out = (float*)d_out;

  constexpr int S = 2048, D = 1024, F = 4096;
  char* ws = (char*)d_ws;
  ushort* xb  = (ushort*)(ws);                                    // [S][D]  4 MB
  ushort* w1t = (ushort*)(ws + (size_t)S * D * 2);                // [F][D]  8 MB
  ushort* w2t = (ushort*)(ws + (size_t)(S * D + F * D) * 2);      // [D][F]  8 MB
  ushort* H   = (ushort*)(ws + (size_t)(S * D + 2 * F * D) * 2);  // [S][F] 16 MB
  // 3 bf16 split-K partials (12 MB) overlay xb+w1t (dead after GEMM1).
  ushort* pb = (ushort*)(ws);

  // fused prep: 2048 cvt blocks + 4096 w1-transpose + 4096 w2-transpose
  hipLaunchKernelGGL(prep, dim3(10240), dim3(32, 8), 0, stream,
                     x, w1, w2, xb, w1t, w2t);
  // GEMM1: H = relu(xb @ w1t^T)  [2048 x 4096], K=1024
  //   grid 16x16 = 256; chunks: ncx=4, cpz=8 (nz=1)
  hipLaunchKernelGGL((gemm_pipe<1>), dim3(256), dim3(512), 0, stream,
                     xb, w1t, (void*)H, nullptr, S, F, D, D, 4, 8);
  // GEMM2: out = H @ w2t^T  [2048 x 1024], K=4096 split 4x1024
  //   grid 4x16x4 = 256; chunks: ncx=1, cpz=2 (nz=4)
  hipLaunchKernelGGL((gemm_pipe<2>), dim3(256), dim3(512), 0, stream,
                     H, w2t, (void*)out, (void*)pb, S, D, F / 4, F, 1, 2);
  // out += p1 + p2 + p3
  hipLaunchKernelGGL(reduce_out, dim3((S * D / 4 + 255) / 256), dim3(256), 0, stream,
                     out, pb, S * D);
}